// Round 10
// baseline (30640.649 us; speedup 1.0000x reference)
//
#include <hip/hip_runtime.h>
#include <math.h>

// ---------------------------------------------------------------------------
// FreqCA: B=8, C=256, H=W=128, NHEADS=8, GROUPS=32.
// Front end (GN -> dw -> pw -> l2norm -> rfft2 -> amp/phase) in FULL fp64.
// FIX (round 8, resubmitted after infra failure): at the self-conjugate rfft2
// bins (ky,kx) in {0,64}x{0,64}, the imaginary part is STRUCTURALLY zero;
// pocketfft produces exact +-0.0 there (sincospi-exact twiddles) so np.angle
// gives 0 or +pi. Our sincos twiddles leak +-1e-16 garbage whose random sign
// flips atan2 to -pi, shifting phase-attention logits by ~2pi-scale amounts
// -> stable winner flips -> decorrelated phase branch (the 0.367 error).
// Force im=+0.0 there.
// Spec stored fp32; attention + iFFT fp64 accumulate; tail convs fp32.
// Per-batch float-equivalent layout (NB batches per pass, adaptive):
//   A xn_d   8,388,608   (4,194,304 doubles)
//   B dw_d   8,388,608   -> later: spat (4,194,304 f) + xn_f (4,194,304 f)
//   C qkvT_d 8,388,608   (one of q/k/v at a time) -> later h1
//   D spec   12,779,520  (6 fp32 slots x 2,129,920; slots 2-5 reused as tre/tim)
//   E rre/rim 4,259,840  (2,129,920 doubles, NB*128-plane chunks) -> later h2
// total 42,205,184 floats = 168.8 MB per batch
// ---------------------------------------------------------------------------

#define TWO_PI_D 6.283185307179586476925286766559
#define ATTN_SCALE_D 0.17677669529663688110021109052621  // 1/sqrt(32)

// ---------------- GroupNorm fp64: one block per (lb,g) ---------------------
__global__ __launch_bounds__(256) void gn64_kernel(
    const float* __restrict__ x, const float* __restrict__ gw,
    const float* __restrict__ gb, double* __restrict__ out, int b0)
{
    int t = threadIdx.x;
    int lb = blockIdx.x >> 5;
    int g  = blockIdx.x & 31;
    size_t src = ((size_t)(b0 + lb) * 32 + g) * 131072;
    size_t dst = (size_t)blockIdx.x * 131072;
    const float* xp = x + src;
    double s = 0.0, ss = 0.0;
    for (int i = t; i < 131072; i += 256) { double v = xp[i]; s += v; ss += v*v; }
    __shared__ double rs[256], rss[256];
    rs[t] = s; rss[t] = ss;
    __syncthreads();
    for (int k = 128; k > 0; k >>= 1) {
        if (t < k) { rs[t] += rs[t+k]; rss[t] += rss[t+k]; }
        __syncthreads();
    }
    double mean = rs[0] * (1.0/131072.0);
    double inv  = 1.0 / sqrt(rss[0] * (1.0/131072.0) - mean*mean + 1e-5);
    for (int i = t; i < 131072; i += 256) {
        int c = (g << 3) + (i >> 14);
        out[dst + i] = ((double)xp[i] - mean) * inv * (double)gw[c] + (double)gb[c];
    }
}

// ---------------- Depthwise 3x3 fp64 ---------------------------------------
__global__ __launch_bounds__(256) void dw64_kernel(
    const double* __restrict__ in, const float* __restrict__ w,
    double* __restrict__ out)
{
    int t = threadIdx.x;
    int bc = blockIdx.x >> 6;
    int y  = ((blockIdx.x & 63) << 1) + (t >> 7);
    int x  = t & 127;
    int c  = bc & 255;
    double wp[9];
    #pragma unroll
    for (int i = 0; i < 9; i++) wp[i] = (double)w[c*9 + i];
    const double* ip = in + ((size_t)bc << 14);
    double acc = 0.0;
    #pragma unroll
    for (int dy = 0; dy < 3; dy++) {
        int yy = y + dy - 1;
        if (yy < 0 || yy > 127) continue;
        const double* row = ip + (yy << 7);
        #pragma unroll
        for (int dx = 0; dx < 3; dx++) {
            int xx = x + dx - 1;
            if (xx >= 0 && xx <= 127) acc += wp[dy*3+dx] * row[xx];
        }
    }
    out[((size_t)bc << 14) + (y << 7) + x] = acc;
}

// ---------------- fp64 1x1-conv GEMM: 64co x 64px tile, Cin=256 ------------
__global__ __launch_bounds__(256) void gemm64_kernel(
    const double* __restrict__ X, const float* __restrict__ W,
    const float* __restrict__ bias, double* __restrict__ C)
{
    int pBase  = blockIdx.x << 6;
    int coBase = blockIdx.y << 6;
    int lb = blockIdx.z;
    int t = threadIdx.x;
    int pxL = (t & 15) << 2;
    int coL = (t >> 4) << 2;
    __shared__ double Ws[16][64];
    __shared__ double Xs[16][66];
    double acc[4][4];
    #pragma unroll
    for (int i = 0; i < 4; i++)
        #pragma unroll
        for (int j = 0; j < 4; j++) acc[i][j] = 0.0;
    size_t xb = ((size_t)lb * 256) << 14;
    for (int k0 = 0; k0 < 256; k0 += 16) {
        __syncthreads();
        for (int i = t; i < 1024; i += 256) {
            int k = i >> 6, co = i & 63;
            Ws[k][co] = (double)W[(size_t)(coBase+co)*256 + k0 + k];
        }
        for (int i = t; i < 1024; i += 256) {
            int k = i >> 6, px = i & 63;
            Xs[k][px] = X[xb + (((size_t)(k0+k)) << 14) + pBase + px];
        }
        __syncthreads();
        for (int k = 0; k < 16; k++) {
            #pragma unroll
            for (int i = 0; i < 4; i++) {
                double wv = Ws[k][coL+i];
                #pragma unroll
                for (int j = 0; j < 4; j++) acc[i][j] += wv * Xs[k][pxL+j];
            }
        }
    }
    #pragma unroll
    for (int i = 0; i < 4; i++) {
        int co = coBase + coL + i;
        double vb = (double)bias[co];
        size_t ob = (((size_t)(lb*256 + co)) << 14) + pBase + pxL;
        #pragma unroll
        for (int j = 0; j < 4; j++) C[ob + j] = acc[i][j] + vb;
    }
}

// ---------------- L2 norm over 256 channels fp64, in place -----------------
__global__ __launch_bounds__(256) void l2n64_kernel(double* __restrict__ q)
{
    int p  = ((blockIdx.x & 63) << 8) + threadIdx.x;
    int lb = blockIdx.x >> 6;
    double* base = q + (((size_t)lb * 256) << 14) + p;
    double ss = 0.0;
    for (int c = 0; c < 256; c++) { double v = base[(size_t)c << 14]; ss += v*v; }
    double inv = 1.0 / fmax(sqrt(ss), 1e-12);
    for (int c = 0; c < 256; c++) base[(size_t)c << 14] *= inv;
}

// ---------------- Forward FFT stage 1 fp64: row DFT ------------------------
__global__ __launch_bounds__(256) void fftrow64_kernel(
    const double* __restrict__ in, double* __restrict__ rre,
    double* __restrict__ rim, int chunkBase)
{
    int rc  = blockIdx.x;          // 16-row chunk 0..7
    int loc = blockIdx.y;          // chunk-local plane
    int gp  = chunkBase + loc;
    int t   = threadIdx.x;
    __shared__ double xs[16][128];
    __shared__ double ct[128], st[128];
    if (t < 128) { double s, c; sincos(TWO_PI_D * t / 128.0, &s, &c); st[t]=s; ct[t]=c; }
    const double* src = in + ((size_t)gp << 14) + ((size_t)rc << 11);
    for (int i = t; i < 2048; i += 256) ((double*)xs)[i] = src[i];
    __syncthreads();
    for (int o = t; o < 1040; o += 256) {
        int r = o / 65, k = o - r*65;
        const double* xr = xs[r];
        double re = 0.0, im = 0.0;
        int m = 0;
        for (int w = 0; w < 128; w++) {
            double xv = xr[w];
            re += xv * ct[m];
            im -= xv * st[m];
            m = (m + k) & 127;
        }
        size_t oi = ((size_t)loc*128 + rc*16 + r)*65 + k;
        rre[oi] = re * 0.0078125;
        rim[oi] = im * 0.0078125;
    }
}

// ---------------- Forward FFT stage 2 fp64 -> fp32 amp/phase slots ---------
__global__ __launch_bounds__(256) void fftcol64_kernel(
    const double* __restrict__ rre, const double* __restrict__ rim,
    float* __restrict__ ampSlot, float* __restrict__ phSlot, int chunkBase)
{
    int kb  = blockIdx.x * 13;
    int loc = blockIdx.y;
    int gp  = chunkBase + loc;     // plane index within slot
    int t   = threadIdx.x;
    __shared__ double cr[128][13], ci[128][13];
    __shared__ double ct[128], st[128];
    if (t < 128) { double s, c; sincos(TWO_PI_D * t / 128.0, &s, &c); st[t]=s; ct[t]=c; }
    for (int i = t; i < 1664; i += 256) {
        int r = i / 13, k = i - r*13;
        size_t si = ((size_t)loc*128 + r)*65 + kb + k;
        cr[r][k] = rre[si];
        ci[r][k] = rim[si];
    }
    __syncthreads();
    float* aD = ampSlot + (size_t)gp * 8320;
    float* pD = phSlot  + (size_t)gp * 8320;
    for (int o = t; o < 1664; o += 256) {
        int k1 = o / 13, k = o - k1*13;
        double re = 0.0, im = 0.0;
        int m = 0;
        for (int r = 0; r < 128; r++) {
            double cc = ct[m], sn = st[m];
            double a = cr[r][k], b = ci[r][k];
            re += a*cc + b*sn;
            im += b*cc - a*sn;
            m = (m + k1) & 127;
        }
        int kxv = kb + k;
        // Self-conjugate bins of rfft2: im is structurally zero. numpy
        // (pocketfft, sincospi-exact twiddles) yields im = +0.0 -> angle in
        // {0, +pi}. Our sincos twiddles leak ~1e-16 random-signed garbage
        // there, flipping atan2 to -pi and decorrelating phase attention.
        if ((k1 == 0 || k1 == 64) && (kxv == 0 || kxv == 64)) im = 0.0;
        int oi = k1*65 + kxv;
        aD[oi] = (float)sqrt(re*re + im*im);
        pD[oi] = (float)atan2(im, re);
    }
}

// ---------------- Fused channel attention: fp32 in, fp64 accum -------------
__global__ __launch_bounds__(256) void attn_fused_kernel(
    const float* __restrict__ qA, const float* __restrict__ kA,
    const float* __restrict__ vA, float* __restrict__ outA)
{
    int bh = blockIdx.x;
    int t  = threadIdx.x;
    const float* qb = qA + (size_t)bh * 32 * 8320;
    const float* kb = kA + (size_t)bh * 32 * 8320;
    const float* vb = vA + (size_t)bh * 32 * 8320;
    float* ob       = outA + (size_t)bh * 32 * 8320;

    __shared__ float qs[32][65], ks[32][65];
    __shared__ double simsh[32][33];

    double acc[4] = {0.0, 0.0, 0.0, 0.0};
    for (int nc = 0; nc < 130; nc++) {
        int n0 = nc * 64;
        for (int i = t; i < 2048; i += 256) {
            int r = i >> 6, c = i & 63;
            qs[r][c] = qb[(size_t)r*8320 + n0 + c];
            ks[r][c] = kb[(size_t)r*8320 + n0 + c];
        }
        __syncthreads();
        #pragma unroll
        for (int e = 0; e < 4; e++) {
            int p4 = t + (e << 8);
            int j = p4 >> 5, k = p4 & 31;
            double a = acc[e];
            #pragma unroll 8
            for (int c = 0; c < 64; c++) a += (double)qs[j][c] * (double)ks[k][c];
            acc[e] = a;
        }
        __syncthreads();
    }
    #pragma unroll
    for (int e = 0; e < 4; e++) {
        int p4 = t + (e << 8);
        simsh[p4 >> 5][p4 & 31] = acc[e] * ATTN_SCALE_D;
    }
    __syncthreads();
    if (t < 32) {
        double m = -1e300;
        for (int k = 0; k < 32; k++) m = fmax(m, simsh[t][k]);
        double s = 0.0;
        for (int k = 0; k < 32; k++) s += exp(simsh[t][k] - m);
        double inv = 1.0 / s;
        for (int k = 0; k < 32; k++) simsh[t][k] = exp(simsh[t][k] - m) * inv;
    }
    __syncthreads();
    for (int n = t; n < 8320; n += 256) {
        float vv[32];
        #pragma unroll
        for (int k = 0; k < 32; k++) vv[k] = vb[(size_t)k*8320 + n];
        for (int j = 0; j < 32; j++) {
            double o = 0.0;
            #pragma unroll
            for (int k = 0; k < 32; k++) o += simsh[j][k] * (double)vv[k];
            ob[(size_t)j*8320 + n] = (float)o;
        }
    }
}

// ---------------- Inverse FFT stage 1 (fp64, e^{+i}) -----------------------
__global__ __launch_bounds__(256) void ifft_col_kernel(
    const float* __restrict__ ampo, const float* __restrict__ pho,
    double* __restrict__ tre, double* __restrict__ tim)
{
    int kb    = blockIdx.x * 13;
    int plane = blockIdx.y;
    int t     = threadIdx.x;
    __shared__ double cr[128][13], cim[128][13];
    __shared__ double ct[128], st[128];
    if (t < 128) { double s, c; sincos(TWO_PI_D * t / 128.0, &s, &c); st[t]=s; ct[t]=c; }
    const float* ab = ampo + (size_t)plane * 8320;
    const float* pb = pho  + (size_t)plane * 8320;
    for (int i = t; i < 1664; i += 256) {
        int k1 = i / 13, k = i - k1*13;
        double a = ab[k1*65 + kb + k];
        double p = pb[k1*65 + kb + k];
        double sp, cp; sincos(p, &sp, &cp);
        cr[k1][k]  = a * cp;
        cim[k1][k] = a * sp;
    }
    __syncthreads();
    for (int o = t; o < 1664; o += 256) {
        int y = o / 13, k = o - y*13;
        double re = 0.0, im = 0.0;
        int m = 0;
        for (int k1 = 0; k1 < 128; k1++) {
            double c = ct[m], s = st[m];
            double a = cr[k1][k], bb = cim[k1][k];
            re += a*c - bb*s;
            im += a*s + bb*c;
            m = (m + y) & 127;
        }
        size_t oi = ((size_t)plane*128 + y)*65 + kb + k;
        tre[oi] = re;
        tim[oi] = im;
    }
}

// ---------------- Inverse FFT stage 2: Hermitian rows (fp64 -> fp32) -------
__global__ __launch_bounds__(256) void ifft_row_kernel(
    const double* __restrict__ tre, const double* __restrict__ tim,
    float* __restrict__ spat)
{
    int rc    = blockIdx.x;
    int plane = blockIdx.y;
    int t     = threadIdx.x;
    __shared__ double tr[16][65], ti[16][65];
    __shared__ double ct[128], st[128];
    if (t < 128) { double s, c; sincos(TWO_PI_D * t / 128.0, &s, &c); st[t]=s; ct[t]=c; }
    for (int i = t; i < 1040; i += 256) {
        int r = i / 65, k = i - r*65;
        size_t si = ((size_t)plane*128 + rc*16 + r)*65 + k;
        tr[r][k] = tre[si];
        ti[r][k] = tim[si];
    }
    __syncthreads();
    for (int o = t; o < 2048; o += 256) {
        int r = o >> 7, x = o & 127;
        double acc = tr[r][0];
        int m = x;
        for (int k = 1; k < 64; k++) {
            acc += 2.0 * (tr[r][k]*ct[m] - ti[r][k]*st[m]);
            m = (m + x) & 127;
        }
        acc += tr[r][64]*ct[m] - ti[r][64]*st[m];
        spat[((size_t)plane << 14) + ((rc*16 + r) << 7) + x] = (float)(acc * 0.0078125);
    }
}

// ---------------- cast fp64 -> fp32 ----------------------------------------
__global__ void cast_d2f_kernel(const double* __restrict__ in,
                                float* __restrict__ out, size_t n)
{
    size_t i = (size_t)blockIdx.x * 256 + threadIdx.x;
    size_t stride = (size_t)gridDim.x * 256;
    for (; i < n; i += stride) out[i] = (float)in[i];
}

// ---------------- fp32 tiled implicit-GEMM conv (tail) ---------------------
template<int R>
__global__ __launch_bounds__(256) void conv_kernel(
    const float* __restrict__ in, const float* __restrict__ wt,
    const float* __restrict__ bias, const float* __restrict__ res,
    float* __restrict__ out, int Cin, int Cout, int act,
    int in_b0, int res_b0, int out_b0)
{
    const int K = Cin * R * R;
    int pBase  = blockIdx.x << 7;
    int coBase = blockIdx.y << 7;
    int lb = blockIdx.z;
    int t = threadIdx.x;
    int tx = t & 15, ty = t >> 4;

    __shared__ float As[8][128];
    __shared__ float Bs[8][128];

    float acc[8][8];
    #pragma unroll
    for (int i = 0; i < 8; i++)
        #pragma unroll
        for (int j = 0; j < 8; j++) acc[i][j] = 0.f;

    int a_co = t >> 1;
    int a_k  = (t & 1) << 2;
    int b_k  = t >> 5;
    int b_p  = (t & 31) << 2;
    const float* wrow = wt + (size_t)(coBase + a_co) * K + a_k;
    const size_t inb = ((size_t)(in_b0 + lb) * Cin) << 14;

    for (int k0 = 0; k0 < K; k0 += 8) {
        float4 av = *(const float4*)(wrow + k0);
        int kk = k0 + b_k;
        float4 bv;
        if (R == 3) {
            int ci = kk / 9; int rr = kk - ci*9; int dy = rr / 3; int dx = rr - dy*3;
            const float* ip = in + inb + ((size_t)ci << 14);
            float tmp[4];
            #pragma unroll
            for (int j = 0; j < 4; j++) {
                int pg = pBase + b_p + j;
                int yy = (pg >> 7) + dy - 1;
                int xx = (pg & 127) + dx - 1;
                tmp[j] = (yy >= 0 && yy < 128 && xx >= 0 && xx < 128) ? ip[(yy << 7) + xx] : 0.f;
            }
            bv = make_float4(tmp[0], tmp[1], tmp[2], tmp[3]);
        } else {
            bv = *(const float4*)(in + inb + ((size_t)kk << 14) + pBase + b_p);
        }
        __syncthreads();
        As[a_k+0][a_co] = av.x; As[a_k+1][a_co] = av.y;
        As[a_k+2][a_co] = av.z; As[a_k+3][a_co] = av.w;
        *(float4*)&Bs[b_k][b_p] = bv;
        __syncthreads();
        #pragma unroll
        for (int k2 = 0; k2 < 8; k2++) {
            float4 A1 = *(const float4*)&As[k2][ty << 2];
            float4 A2 = *(const float4*)&As[k2][64 + (ty << 2)];
            float4 B1 = *(const float4*)&Bs[k2][tx << 2];
            float4 B2 = *(const float4*)&Bs[k2][64 + (tx << 2)];
            float a0[8] = {A1.x,A1.y,A1.z,A1.w,A2.x,A2.y,A2.z,A2.w};
            float b0v[8] = {B1.x,B1.y,B1.z,B1.w,B2.x,B2.y,B2.z,B2.w};
            #pragma unroll
            for (int i = 0; i < 8; i++)
                #pragma unroll
                for (int j = 0; j < 8; j++) acc[i][j] += a0[i] * b0v[j];
        }
    }

    #pragma unroll
    for (int i = 0; i < 8; i++) {
        int co = coBase + ((i < 4) ? ((ty << 2) + i) : (64 + (ty << 2) + i - 4));
        size_t rbo = (((size_t)(out_b0 + lb) * Cout + co) << 14) + pBase;
        size_t rbr = (((size_t)(res_b0 + lb) * Cout + co) << 14) + pBase;
        float vb = bias ? bias[co] : 0.f;
        #pragma unroll
        for (int jh = 0; jh < 2; jh++) {
            int colo = (jh == 0) ? (tx << 2) : (64 + (tx << 2));
            float4 v;
            v.x = acc[i][jh*4+0] + vb;
            v.y = acc[i][jh*4+1] + vb;
            v.z = acc[i][jh*4+2] + vb;
            v.w = acc[i][jh*4+3] + vb;
            if (act == 1) {
                v.x = v.x / (1.f + expf(-v.x));
                v.y = v.y / (1.f + expf(-v.y));
                v.z = v.z / (1.f + expf(-v.z));
                v.w = v.w / (1.f + expf(-v.w));
            }
            if (res) {
                float4 r4 = *(const float4*)(res + rbr + colo);
                v.x += r4.x; v.y += r4.y; v.z += r4.z; v.w += r4.w;
            }
            *(float4*)(out + rbo + colo) = v;
        }
    }
}

// ---------------------------------------------------------------------------
extern "C" void kernel_launch(void* const* d_in, const int* in_sizes, int n_in,
                              void* d_out, int out_size, void* d_ws, size_t ws_size,
                              hipStream_t stream) {
    (void)in_sizes; (void)n_in; (void)out_size;
    const float* x    = (const float*)d_in[0];
    const float* gn_w = (const float*)d_in[1];
    const float* gn_b = (const float*)d_in[2];
    const float* dw_w = (const float*)d_in[3];
    const float* pw_w = (const float*)d_in[4];
    const float* pw_b = (const float*)d_in[5];
    const float* ao_w = (const float*)d_in[6];
    const float* ao_b = (const float*)d_in[7];
    const float* f1_w = (const float*)d_in[8];
    const float* f2_w = (const float*)d_in[9];
    const float* f3_w = (const float*)d_in[10];
    const float* f3_b = (const float*)d_in[11];
    float* outp = (float*)d_out;

    // per-batch region sizes in float-equivalents
    const size_t F_XND  = 8388608;    // xn_d (doubles)
    const size_t F_B    = 8388608;    // dw_d -> spat + xn_f
    const size_t F_C    = 8388608;    // qkvT_d -> h1
    const size_t F_SLOT = 2129920;    // fp32 spec slot
    const size_t F_SPEC = 6 * F_SLOT; // 12,779,520
    const size_t F_E    = 4259840;    // rre/rim doubles -> h2
    const size_t F_TOT  = F_XND + F_B + F_C + F_SPEC + F_E; // 42,205,184

    int NB = 0;
    for (int cand : {8, 4, 2, 1}) {
        if ((size_t)cand * F_TOT * 4 <= ws_size) { NB = cand; break; }
    }
    if (NB == 0) return;   // workspace too small: clean failure, no OOB crash

    float*  wsf  = (float*)d_ws;
    double* xn_d = (double*)wsf;                               // [A]
    float*  Breg = wsf + (size_t)NB * F_XND;                   // [B]
    double* dw_d = (double*)Breg;
    float*  spat = Breg;                                       // lower half of B
    float*  xn_f = Breg + (size_t)NB * 4194304;                // upper half of B
    float*  Creg = Breg + (size_t)NB * F_B;                    // [C]
    double* qkvT = (double*)Creg;
    float*  h1   = Creg;
    float*  spec = Creg + (size_t)NB * F_C;                    // [D]
    size_t  ss   = (size_t)NB * F_SLOT;
    double* tre  = (double*)(spec + 2*ss);                     // slots 2-3
    double* tim  = (double*)(spec + 4*ss);                     // slots 4-5
    float*  Ereg = spec + 6*ss;                                // [E]
    double* rre  = (double*)Ereg;
    double* rim  = rre + (size_t)NB * 1064960;                 // NB*128*8320
    float*  h2   = Ereg;

    const int passes = 8 / NB;
    for (int p = 0; p < passes; p++) {
        int b0 = p * NB;
        // 1. GroupNorm fp64 -> xn_d
        gn64_kernel<<<NB*32, 256, 0, stream>>>(x, gn_w, gn_b, xn_d, b0);
        // 2. depthwise 3x3 fp64 -> dw_d
        dw64_kernel<<<NB*256*64, 256, 0, stream>>>(xn_d, dw_w, dw_d);
        // 3. per-T: pointwise fp64 GEMM -> qkvT_d, l2norm fp64, rfft2 fp64
        for (int T = 0; T < 3; T++) {
            gemm64_kernel<<<dim3(256, 4, NB), 256, 0, stream>>>(
                dw_d, pw_w + (size_t)T*65536, pw_b + T*256, qkvT);
            l2n64_kernel<<<NB*64, 256, 0, stream>>>(qkvT);
            for (int chunk = 0; chunk < 2; chunk++) {
                fftrow64_kernel<<<dim3(8, NB*128), 256, 0, stream>>>(
                    qkvT, rre, rim, chunk*NB*128);
                fftcol64_kernel<<<dim3(5, NB*128), 256, 0, stream>>>(
                    rre, rim, spec + (size_t)(2*T)*ss, spec + (size_t)(2*T+1)*ss,
                    chunk*NB*128);
            }
        }
        // 4. channel attention: amp (0,2,4 -> 0), phase (1,3,5 -> 1)
        attn_fused_kernel<<<NB*8, 256, 0, stream>>>(spec + 0*ss, spec + 2*ss,
                                                    spec + 4*ss, spec + 0*ss);
        attn_fused_kernel<<<NB*8, 256, 0, stream>>>(spec + 1*ss, spec + 3*ss,
                                                    spec + 5*ss, spec + 1*ss);
        // 5. irfft2: slots 0,1 -> tre/tim (slots 2-5) -> spat
        ifft_col_kernel<<<dim3(5, NB*256), 256, 0, stream>>>(spec + 0*ss, spec + 1*ss,
                                                             tre, tim);
        ifft_row_kernel<<<dim3(8, NB*256), 256, 0, stream>>>(tre, tim, spat);
        // 6. cast xn_d -> xn_f for the ao residual
        cast_d2f_kernel<<<2048, 256, 0, stream>>>(xn_d, xn_f, (size_t)NB * 4194304);
        // 7. ao 1x1 (+bias) + xn residual -> attn (in d_out)
        conv_kernel<1><<<dim3(128, 2, NB), 256, 0, stream>>>(
            spat, ao_w, ao_b, xn_f, outp, 256, 256, 0, 0, 0, b0);
        // 8. f1 3x3 256->512 + SiLU
        conv_kernel<3><<<dim3(128, 4, NB), 256, 0, stream>>>(
            outp, f1_w, nullptr, nullptr, h1, 256, 512, 1, b0, 0, 0);
        // 9. f2 3x3 512->256
        conv_kernel<3><<<dim3(128, 2, NB), 256, 0, stream>>>(
            h1, f2_w, nullptr, nullptr, h2, 512, 256, 0, 0, 0, 0);
        // 10. f3 1x1 (+bias) + attn residual, in place on d_out
        conv_kernel<1><<<dim3(128, 2, NB), 256, 0, stream>>>(
            h2, f3_w, f3_b, outp, outp, 256, 256, 0, 0, b0, b0);
    }
}